// Round 3
// baseline (238.743 us; speedup 1.0000x reference)
//
#include <hip/hip_runtime.h>

typedef short bf16x8 __attribute__((ext_vector_type(8)));
typedef float f32x4 __attribute__((ext_vector_type(4)));

__device__ __forceinline__ unsigned short f2bf(float f) {
    unsigned u = __float_as_uint(f);
    u += 0x7FFFu + ((u >> 16) & 1u);      // round-to-nearest-even
    return (unsigned short)(u >> 16);
}
__device__ __forceinline__ void gload_lds16(const void* g, void* l) {
    __builtin_amdgcn_global_load_lds(
        (const __attribute__((address_space(1))) void*)g,
        (__attribute__((address_space(3))) void*)l,
        16, 0, 0);
}

// ---------------------------------------------------------------- prep (one launch):
// blocks [0,16384): convert u -> bf16 A' with ROW PERMUTATION
//   A'[p*128 + b*16 + ll] = u[b*2048 + p*16 + ll]
// blocks [16384,17408): Bt[j][k] interleaved:  g=j>>5, w=j&31, n=g*16+(w&15)
//   Bt[j][k] = (w<16 ? Br[k][n] : Bi[k][n])          (1024x1024 bf16)
// blocks [17408,18432): Dt[h][j]: Dt[h][j] = (w<16 ? Cr[n][h] : -Ci[n][h])
__global__ void prep(const float* __restrict__ u,
                     const float* __restrict__ Br, const float* __restrict__ Bi,
                     const float* __restrict__ Cr, const float* __restrict__ Ci,
                     unsigned short* __restrict__ A, unsigned short* __restrict__ Bt,
                     unsigned short* __restrict__ Dt) {
    int bid = blockIdx.x;
    if (bid < 16384) {
        int i = bid * 256 + threadIdx.x;        // float4 id, out-order
        int ro = i >> 8, c4 = i & 255;          // out row (permuted), col-group
        int p = ro >> 7, b = (ro >> 4) & 7, ll = ro & 15;
        int ri = b * 2048 + p * 16 + ll;        // source row in u
        float4 v = ((const float4*)u)[(size_t)ri * 256 + c4];
        ushort4 o; o.x = f2bf(v.x); o.y = f2bf(v.y); o.z = f2bf(v.z); o.w = f2bf(v.w);
        ((ushort4*)A)[i] = o;
        return;
    }
    __shared__ unsigned short tile[32][33];
    int id = bid - 16384;          // [0, 2048)
    int z  = id >> 10;             // 0: Bt, 1: Dt
    int t  = id & 1023;
    int jt = t >> 5, kt = t & 31;  // j-tile (32 cols of out), k/h-tile
    int tx = threadIdx.x & 31, ty = threadIdx.x >> 5;   // 32 x 8
    if (z == 0) {
        for (int i2 = ty; i2 < 32; i2 += 8) {          // i2 = k offset
            int k = kt * 32 + i2;
            float v = (tx < 16) ? Br[(size_t)k * 512 + jt * 16 + tx]
                                : Bi[(size_t)k * 512 + jt * 16 + (tx & 15)];
            tile[tx][i2] = f2bf(v);                    // tile[w][k]
        }
        __syncthreads();
        for (int i2 = ty; i2 < 32; i2 += 8)            // i2 = w
            Bt[(size_t)(jt * 32 + i2) * 1024 + kt * 32 + tx] = tile[i2][tx];
    } else {
        for (int i2 = ty; i2 < 32; i2 += 8) {          // i2 = w
            float v = (i2 < 16) ? Cr[(size_t)(jt * 16 + i2) * 1024 + kt * 32 + tx]
                                : -Ci[(size_t)(jt * 16 + (i2 & 15)) * 1024 + kt * 32 + tx];
            tile[i2][tx] = f2bf(v);                    // tile[w][h]
        }
        __syncthreads();
        for (int i2 = ty; i2 < 32; i2 += 8)            // i2 = h offset
            Dt[(size_t)(kt * 32 + i2) * 1024 + jt * 32 + tx] = tile[tx][i2];
    }
}

// ---------------------------------------------------------------- K-loop (shared by both GEMMs)
// 256x256 tile, BK=64, 8 waves (2 wr x 4 wc), wave tile 128x64, acc[8][4].
// A: LDS double-buffer 2 x 32KB, rows of 128B, swizzle byte ^= ((row&7)<<4)
//    (pre-XOR'd global source + linear gload_lds dest + XOR'd ds_read -> conflict-free:
//    granule class lq^(lm&7) spans all 8 classes uniformly, 8 lanes each = min 8 cyc).
// B: 2 MB, L2-resident -> direct global->reg, double-buffered 1 K-tile ahead.
// Issue order pinned (sched_barrier between ASTAGE and BLOAD) so vmcnt(8) at tile end
// retires exactly the 4 A-stages; the 8 B-loads stay in flight across the barrier.
// lgkmcnt(0) before the barrier: this tile's ds_reads retire before next tile's
// gload_lds overwrites that buffer.

#define KSETUP(AP, BP)                                                              \
    const int tid = threadIdx.x, lane = tid & 63, wave = tid >> 6;                  \
    const int lm = lane & 15, lq = lane >> 4;                                       \
    const int wr = wave >> 2, wc = wave & 3;                                        \
    const int id = blockIdx.x;                                                      \
    const int T = (id & 7) * 32 + (id >> 3);                                        \
    const int bm = T >> 2, bn = T & 3;                                              \
    const int row0 = bm * 256, col0 = bn * 256;                                     \
    const int srow = tid >> 3;                                                      \
    const int xoff = ((tid & 7) ^ (srow & 7)) << 4;                                 \
    const char* sA0 = (const char*)(AP) + (size_t)(row0 + srow) * 2048 + xoff;      \
    const char* sA1 = sA0 + 64 * 2048;                                              \
    const char* sA2 = sA1 + 64 * 2048;                                              \
    const char* sA3 = sA2 + 64 * 2048;                                              \
    char* dA0 = (char*)LDS + tid * 16;                                              \
    char* dA1 = dA0 + 8192; char* dA2 = dA1 + 8192; char* dA3 = dA2 + 8192;         \
    const char* pB0 = (const char*)(BP) + (size_t)(col0 + wc * 64 + lm) * 2048 + lq * 16; \
    const char* pB1 = pB0 + 16 * 2048;                                              \
    const char* pB2 = pB1 + 16 * 2048;                                              \
    const char* pB3 = pB2 + 16 * 2048;                                              \
    const char* rA0 = (char*)LDS + (wr * 128 + lm) * 128 + ((lq ^ (lm & 7)) << 4);  \
    const char* rA1 = (char*)LDS + (wr * 128 + lm) * 128 + (((4 | lq) ^ (lm & 7)) << 4); \
    f32x4 acc[8][4] = {};                                                           \
    bf16x8 bA[8], bB[8];

#define ASTAGE(DOFF)                                                                \
    gload_lds16(sA0, dA0 + (DOFF)); gload_lds16(sA1, dA1 + (DOFF));                 \
    gload_lds16(sA2, dA2 + (DOFF)); gload_lds16(sA3, dA3 + (DOFF));                 \
    sA0 += 128; sA1 += 128; sA2 += 128; sA3 += 128;

#define BLOAD(DST)                                                                  \
    DST[0] = *(const bf16x8*)(pB0);     DST[1] = *(const bf16x8*)(pB0 + 64);        \
    DST[2] = *(const bf16x8*)(pB1);     DST[3] = *(const bf16x8*)(pB1 + 64);        \
    DST[4] = *(const bf16x8*)(pB2);     DST[5] = *(const bf16x8*)(pB2 + 64);        \
    DST[6] = *(const bf16x8*)(pB3);     DST[7] = *(const bf16x8*)(pB3 + 64);        \
    pB0 += 128; pB1 += 128; pB2 += 128; pB3 += 128;

#define KCOMPUTE(CB, BSRC)                                                          \
    __builtin_amdgcn_s_setprio(1);                                                  \
    _Pragma("unroll")                                                               \
    for (int h = 0; h < 2; ++h) {                                                   \
        bf16x8 af[8];                                                               \
        _Pragma("unroll")                                                           \
        for (int mi = 0; mi < 4; ++mi) {                                            \
            af[mi * 2]     = *(const bf16x8*)(rA0 + (CB) * 32768 + h * 8192 + mi * 2048); \
            af[mi * 2 + 1] = *(const bf16x8*)(rA1 + (CB) * 32768 + h * 8192 + mi * 2048); \
        }                                                                           \
        _Pragma("unroll")                                                           \
        for (int mi = 0; mi < 4; ++mi)                                              \
            _Pragma("unroll")                                                       \
            for (int ni = 0; ni < 4; ++ni) {                                        \
                acc[h * 4 + mi][ni] = __builtin_amdgcn_mfma_f32_16x16x32_bf16(      \
                    af[mi * 2], BSRC[ni * 2], acc[h * 4 + mi][ni], 0, 0, 0);        \
                acc[h * 4 + mi][ni] = __builtin_amdgcn_mfma_f32_16x16x32_bf16(      \
                    af[mi * 2 + 1], BSRC[ni * 2 + 1], acc[h * 4 + mi][ni], 0, 0, 0);\
            }                                                                       \
    }                                                                               \
    __builtin_amdgcn_s_setprio(0);

#define KTILE(CB, BCUR, BNXT)                                                       \
    ASTAGE((CB ^ 1) * 32768)                                                        \
    __builtin_amdgcn_sched_barrier(0);                                              \
    BLOAD(BNXT)                                                                     \
    __builtin_amdgcn_sched_barrier(0);                                              \
    KCOMPUTE(CB, BCUR)                                                              \
    __builtin_amdgcn_sched_barrier(0);                                              \
    asm volatile("s_waitcnt vmcnt(8) lgkmcnt(0)");                                  \
    __builtin_amdgcn_sched_barrier(0);                                              \
    __builtin_amdgcn_s_barrier();                                                   \
    __builtin_amdgcn_sched_barrier(0);

#define KPROLOGUE()                                                                 \
    ASTAGE(0)                                                                       \
    __builtin_amdgcn_sched_barrier(0);                                              \
    BLOAD(bA)                                                                       \
    __builtin_amdgcn_sched_barrier(0);                                              \
    asm volatile("s_waitcnt vmcnt(8)");                                             \
    __builtin_amdgcn_s_barrier();                                                   \
    __builtin_amdgcn_sched_barrier(0);

#define KMAIN()                                                                     \
    KPROLOGUE()                                                                     \
    for (int tt = 0; tt < 7; ++tt) {                                                \
        KTILE(0, bA, bB)                                                            \
        KTILE(1, bB, bA)                                                            \
    }                                                                               \
    KTILE(0, bA, bB)                                                                \
    KCOMPUTE(1, bB)

// ---------------------------------------------------------------- GEMM1 + fused phase/cumsum
__global__ __launch_bounds__(512, 2)
void gemm1_fused(const unsigned short* __restrict__ A, const unsigned short* __restrict__ Bt,
                 const int* __restrict__ len, const float* __restrict__ nu_log,
                 const float* __restrict__ th_log, unsigned short* __restrict__ X) {
    __shared__ __attribute__((aligned(16))) char LDS[65536];   // 64 KB (A dbuf only)
    KSETUP(A, Bt)
    KMAIN()

    // ---- fused epilogue: Lambda^e phase multiply + cumsum over b (b == m-block) ----
    const float inv2pi = 0.15915494309189535f;
    const float twopi  = 6.283185307179586f;
    int lenv[8];
#pragma unroll
    for (int b = 0; b < 8; ++b) lenv[b] = len[b];
    const int pnl  = 2 * bm + wr;
    const int l_lo = pnl * 16 + lq * 4;
#pragma unroll
    for (int gg = 0; gg < 2; ++gg) {
        const int cbase = col0 + wc * 64 + gg * 32;    // real at +lm, imag at +16+lm
        const int n = (cbase >> 5) * 16 + lm;
        const float nu = __expf(nu_log[n]);
        const float rv = __expf(th_log[n]) * inv2pi;
#pragma unroll
        for (int r = 0; r < 4; ++r) {
            const int l = l_lo + r;
            const float lp1 = (float)(l + 1);
            float sr = 0.f, si = 0.f;
#pragma unroll
            for (int b = 0; b < 8; ++b) {              // in-register cumsum over b
                float e = fmaxf((float)lenv[b] - lp1, 0.f);
                float mag = __expf(-e * nu);
                float ar = e * rv; ar -= floorf(ar);
                float sn, cs; __sincosf(ar * twopi, &sn, &cs);
                float Lr = mag * cs, Li = mag * sn;
                float Bur = acc[b][2 * gg][r], Bui = acc[b][2 * gg + 1][r];
                sr += Lr * Bur - Li * Bui;
                si += Lr * Bui + Li * Bur;
                size_t ro = ((size_t)b * 2048 + l) * 1024;
                X[ro + cbase + lm]      = f2bf(sr);
                X[ro + cbase + lm + 16] = f2bf(si);
            }
        }
    }
}

// ---------------------------------------------------------------- GEMM2: y = X x Dt
__global__ __launch_bounds__(512, 2)
void gemm2(const unsigned short* __restrict__ X, const unsigned short* __restrict__ Dt,
           float* __restrict__ Y) {
    __shared__ __attribute__((aligned(16))) char LDS[65536];
    KSETUP(X, Dt)
    KMAIN()

#pragma unroll
    for (int mi = 0; mi < 8; ++mi) {
#pragma unroll
        for (int ni = 0; ni < 4; ++ni) {
            int c  = col0 + wc * 64 + ni * 16 + lm;
            int r0 = row0 + wr * 128 + mi * 16 + lq * 4;
#pragma unroll
            for (int r = 0; r < 4; ++r)
                Y[(size_t)(r0 + r) * 1024 + c] = acc[mi][ni][r];
        }
    }
}

// ----------------------------------------------------------------
extern "C" void kernel_launch(void* const* d_in, const int* in_sizes, int n_in,
                              void* d_out, int out_size, void* d_ws, size_t ws_size,
                              hipStream_t stream) {
    const float* u      = (const float*)d_in[0];   // (8,2048,1024) f32
    const int*   len    = (const int*)d_in[1];     // (8,)
    const float* nu_log = (const float*)d_in[2];   // (512,)
    const float* th_log = (const float*)d_in[3];   // (512,)
    const float* Br     = (const float*)d_in[4];   // (1024,512)
    const float* Bi     = (const float*)d_in[5];   // (1024,512)
    const float* Cr     = (const float*)d_in[6];   // (512,1024)
    const float* Ci     = (const float*)d_in[7];   // (512,1024)
    float* y = (float*)d_out;                      // (8,2048,1024) f32

    char* ws = (char*)d_ws;
    unsigned short* A  = (unsigned short*)(ws);                 // 32 MB  (u bf16, rows permuted)
    unsigned short* X  = (unsigned short*)(ws + 33554432);      // 32 MB  (phase+cumsum result)
    unsigned short* Bt = (unsigned short*)(ws + 67108864);      //  2 MB
    unsigned short* Dt = (unsigned short*)(ws + 69206016);      //  2 MB

    prep<<<18432, 256, 0, stream>>>(u, Br, Bi, Cr, Ci, A, Bt, Dt);
    gemm1_fused<<<256, 512, 0, stream>>>(A, Bt, len, nu_log, th_log, X);
    gemm2<<<256, 512, 0, stream>>>(X, Dt, y);
}

// Round 5
// 227.530 us; speedup vs baseline: 1.0493x; 1.0493x over previous
//
#include <hip/hip_runtime.h>

typedef short bf16x8 __attribute__((ext_vector_type(8)));
typedef float f32x4 __attribute__((ext_vector_type(4)));

__device__ __forceinline__ unsigned short f2bf(float f) {
    unsigned u = __float_as_uint(f);
    u += 0x7FFFu + ((u >> 16) & 1u);      // round-to-nearest-even
    return (unsigned short)(u >> 16);
}
__device__ __forceinline__ void gload_lds16(const void* g, void* l) {
    __builtin_amdgcn_global_load_lds(
        (const __attribute__((address_space(1))) void*)g,
        (__attribute__((address_space(3))) void*)l,
        16, 0, 0);
}

// ---------------------------------------------------------------- prep (one launch):
// blocks [0,16384): convert u -> bf16 A' with ROW PERMUTATION
//   A'[p*128 + b*16 + ll] = u[b*2048 + p*16 + ll]
// blocks [16384,17408): Bt[j][k] interleaved:  g=j>>5, w=j&31, n=g*16+(w&15)
//   Bt[j][k] = (w<16 ? Br[k][n] : Bi[k][n])          (1024x1024 bf16)
// blocks [17408,18432): Dt[h][j]: Dt[h][j] = (w<16 ? Cr[n][h] : -Ci[n][h])
__global__ void prep(const float* __restrict__ u,
                     const float* __restrict__ Br, const float* __restrict__ Bi,
                     const float* __restrict__ Cr, const float* __restrict__ Ci,
                     unsigned short* __restrict__ A, unsigned short* __restrict__ Bt,
                     unsigned short* __restrict__ Dt) {
    int bid = blockIdx.x;
    if (bid < 16384) {
        int i = bid * 256 + threadIdx.x;        // float4 id, out-order
        int ro = i >> 8, c4 = i & 255;          // out row (permuted), col-group
        int p = ro >> 7, b = (ro >> 4) & 7, ll = ro & 15;
        int ri = b * 2048 + p * 16 + ll;        // source row in u
        float4 v = ((const float4*)u)[(size_t)ri * 256 + c4];
        ushort4 o; o.x = f2bf(v.x); o.y = f2bf(v.y); o.z = f2bf(v.z); o.w = f2bf(v.w);
        ((ushort4*)A)[i] = o;
        return;
    }
    __shared__ unsigned short tile[32][33];
    int id = bid - 16384;          // [0, 2048)
    int z  = id >> 10;             // 0: Bt, 1: Dt
    int t  = id & 1023;
    int jt = t >> 5, kt = t & 31;  // j-tile (32 cols of out), k/h-tile
    int tx = threadIdx.x & 31, ty = threadIdx.x >> 5;   // 32 x 8
    if (z == 0) {
        for (int i2 = ty; i2 < 32; i2 += 8) {          // i2 = k offset
            int k = kt * 32 + i2;
            float v = (tx < 16) ? Br[(size_t)k * 512 + jt * 16 + tx]
                                : Bi[(size_t)k * 512 + jt * 16 + (tx & 15)];
            tile[tx][i2] = f2bf(v);                    // tile[w][k]
        }
        __syncthreads();
        for (int i2 = ty; i2 < 32; i2 += 8)            // i2 = w
            Bt[(size_t)(jt * 32 + i2) * 1024 + kt * 32 + tx] = tile[i2][tx];
    } else {
        for (int i2 = ty; i2 < 32; i2 += 8) {          // i2 = w
            float v = (i2 < 16) ? Cr[(size_t)(jt * 16 + i2) * 1024 + kt * 32 + tx]
                                : -Ci[(size_t)(jt * 16 + (i2 & 15)) * 1024 + kt * 32 + tx];
            tile[i2][tx] = f2bf(v);                    // tile[w][h]
        }
        __syncthreads();
        for (int i2 = ty; i2 < 32; i2 += 8)            // i2 = h offset
            Dt[(size_t)(kt * 32 + i2) * 1024 + jt * 32 + tx] = tile[tx][i2];
    }
}

// ---------------------------------------------------------------- K-loop (shared by both GEMMs)
// 128x256 tile, BK=64, grid 512 = 2 blocks/CU (two INDEPENDENT barrier domains -> TLP
// hides per-tile latency; round-3's 1-block/CU lockstep was the regression).
// 4 waves, wave tile 128x64, acc[8][4] (AGPR).
// A: LDS ring of 4 x 16KB buffers, staged 2 tiles ahead via global_load_lds.
//    Rows 128B, swizzle LDS[row][s] = G[row][s ^ (row&7)] (pre-XOR'd global source,
//    linear LDS dest, XOR'd ds_read) -> 8 lanes per 16B slot = conflict-free floor.
// B: 2 MB L2-resident -> direct global->reg, double-buffered 1 tile ahead.
// Steady state has NO explicit vmcnt: in-order vmcnt retirement means the compiler's
// own wait on B(t) registers (issued after stage(t+1)) transitively retires the
// A-stage for the buffer read next tile, before this tile's end barrier.
// lgkmcnt(0) before barrier: this tile's ds_reads retire before buffer reuse.

#define SBAR __builtin_amdgcn_sched_barrier(0)

#define KSETUP(AP, BP)                                                              \
    const int tid = threadIdx.x, lane = tid & 63, wave = tid >> 6;                  \
    const int lm = lane & 15, lq = lane >> 4;                                       \
    const int wc = wave;                                                            \
    const int id = blockIdx.x;                                                      \
    const int T = (id & 7) * 64 + (id >> 3);                                        \
    const int bm = T >> 2, bn = T & 3;                                              \
    const int row0 = bm * 128, col0 = bn * 256;                                     \
    const int srow = tid >> 3;                                                      \
    const int xoff = ((tid & 7) ^ (srow & 7)) << 4;                                 \
    const char* sA0 = (const char*)(AP) + (size_t)(row0 + srow) * 2048 + xoff;      \
    const char* sA1 = sA0 + 32 * 2048;                                              \
    const char* sA2 = sA1 + 32 * 2048;                                              \
    const char* sA3 = sA2 + 32 * 2048;                                              \
    char* dA0 = (char*)LDS + tid * 16;                                              \
    char* dA1 = dA0 + 4096; char* dA2 = dA1 + 4096; char* dA3 = dA2 + 4096;         \
    const char* pB0 = (const char*)(BP) + (size_t)(col0 + wc * 64 + lm) * 2048 + lq * 16; \
    const char* pB1 = pB0 + 16 * 2048;                                              \
    const char* pB2 = pB1 + 16 * 2048;                                              \
    const char* pB3 = pB2 + 16 * 2048;                                              \
    const char* rA0 = (char*)LDS + lm * 128 + ((lq ^ (lm & 7)) << 4);               \
    const char* rA1 = (char*)LDS + lm * 128 + (((4 | lq) ^ (lm & 7)) << 4);         \
    f32x4 acc[8][4] = {};                                                           \
    bf16x8 bA[8], bB[8];

#define ASTAGE(DOFF)                                                                \
    gload_lds16(sA0, dA0 + (DOFF)); gload_lds16(sA1, dA1 + (DOFF));                 \
    gload_lds16(sA2, dA2 + (DOFF)); gload_lds16(sA3, dA3 + (DOFF));                 \
    sA0 += 128; sA1 += 128; sA2 += 128; sA3 += 128;

#define BLOAD(DST)                                                                  \
    DST[0] = *(const bf16x8*)(pB0);     DST[1] = *(const bf16x8*)(pB0 + 64);        \
    DST[2] = *(const bf16x8*)(pB1);     DST[3] = *(const bf16x8*)(pB1 + 64);        \
    DST[4] = *(const bf16x8*)(pB2);     DST[5] = *(const bf16x8*)(pB2 + 64);        \
    DST[6] = *(const bf16x8*)(pB3);     DST[7] = *(const bf16x8*)(pB3 + 64);        \
    pB0 += 128; pB1 += 128; pB2 += 128; pB3 += 128;

#define KCOMPUTE(CB, BSRC)                                                          \
    __builtin_amdgcn_s_setprio(1);                                                  \
    _Pragma("unroll")                                                               \
    for (int h = 0; h < 2; ++h) {                                                   \
        bf16x8 af[8];                                                               \
        _Pragma("unroll")                                                           \
        for (int mi = 0; mi < 4; ++mi) {                                            \
            af[mi * 2]     = *(const bf16x8*)(rA0 + (CB) * 16384 + h * 8192 + mi * 2048); \
            af[mi * 2 + 1] = *(const bf16x8*)(rA1 + (CB) * 16384 + h * 8192 + mi * 2048); \
        }                                                                           \
        _Pragma("unroll")                                                           \
        for (int mi = 0; mi < 4; ++mi)                                              \
            _Pragma("unroll")                                                       \
            for (int ni = 0; ni < 4; ++ni) {                                        \
                acc[h * 4 + mi][ni] = __builtin_amdgcn_mfma_f32_16x16x32_bf16(      \
                    af[mi * 2], BSRC[ni * 2], acc[h * 4 + mi][ni], 0, 0, 0);        \
                acc[h * 4 + mi][ni] = __builtin_amdgcn_mfma_f32_16x16x32_bf16(      \
                    af[mi * 2 + 1], BSRC[ni * 2 + 1], acc[h * 4 + mi][ni], 0, 0, 0);\
            }                                                                       \
    }                                                                               \
    __builtin_amdgcn_s_setprio(0);

#define KFENCE()                                                                    \
    asm volatile("s_waitcnt lgkmcnt(0)");                                           \
    SBAR;                                                                           \
    __builtin_amdgcn_s_barrier();                                                   \
    SBAR;

#define KTILE_SB(q_, BCUR, BNXT)                                                    \
    ASTAGE((((q_) + 2) & 3) * 16384)                                                \
    SBAR;                                                                           \
    BLOAD(BNXT)                                                                     \
    SBAR;                                                                           \
    KCOMPUTE(q_, BCUR)                                                              \
    SBAR;                                                                           \
    KFENCE()

#define KMAIN()                                                                     \
    ASTAGE(0)                                                                       \
    ASTAGE(16384)                                                                   \
    SBAR;                                                                           \
    BLOAD(bA)                                                                       \
    SBAR;                                                                           \
    asm volatile("s_waitcnt vmcnt(12)");                                            \
    __builtin_amdgcn_s_barrier();                                                   \
    SBAR;                                                                           \
    for (int tt = 0; tt < 3; ++tt) {                                                \
        KTILE_SB(0, bA, bB)                                                         \
        KTILE_SB(1, bB, bA)                                                         \
        KTILE_SB(2, bA, bB)                                                         \
        KTILE_SB(3, bB, bA)                                                         \
    }                                                                               \
    KTILE_SB(0, bA, bB)                                                             \
    KTILE_SB(1, bB, bA)                                                             \
    /* t=14: no stage left */                                                       \
    BLOAD(bB)                                                                       \
    SBAR;                                                                           \
    KCOMPUTE(2, bA)                                                                 \
    SBAR;                                                                           \
    KFENCE()                                                                        \
    /* t=15: compute only, no barrier after */                                      \
    KCOMPUTE(3, bB)

// ---------------------------------------------------------------- GEMM1 + fused phase/cumsum
// Block's 128 A'-rows = one l-panel (16 l's) x ALL 8 batches (b == acc m-block):
// phase multiply + cumsum over b fully in-register.
__global__ __launch_bounds__(256, 2)
void gemm1_fused(const unsigned short* __restrict__ A, const unsigned short* __restrict__ Bt,
                 const int* __restrict__ len, const float* __restrict__ nu_log,
                 const float* __restrict__ th_log, unsigned short* __restrict__ X) {
    __shared__ __attribute__((aligned(16))) char LDS[65536];   // 4-ring x 16 KB
    KSETUP(A, Bt)
    KMAIN()

    const float inv2pi = 0.15915494309189535f;
    const float twopi  = 6.283185307179586f;
    int lenv[8];
#pragma unroll
    for (int b = 0; b < 8; ++b) lenv[b] = len[b];
    const int l_lo = bm * 16 + lq * 4;
#pragma unroll
    for (int gg = 0; gg < 2; ++gg) {
        const int cbase = col0 + wc * 64 + gg * 32;    // real at +lm, imag at +16+lm
        const int n = (cbase >> 5) * 16 + lm;
        const float nu = __expf(nu_log[n]);
        const float rv = __expf(th_log[n]) * inv2pi;
#pragma unroll
        for (int r = 0; r < 4; ++r) {
            const int l = l_lo + r;
            const float lp1 = (float)(l + 1);
            float sr = 0.f, si = 0.f;
#pragma unroll
            for (int b = 0; b < 8; ++b) {              // in-register cumsum over b
                float e = fmaxf((float)lenv[b] - lp1, 0.f);
                float mag = __expf(-e * nu);
                float ar = e * rv; ar -= floorf(ar);
                float sn, cs; __sincosf(ar * twopi, &sn, &cs);
                float Lr = mag * cs, Li = mag * sn;
                float Bur = acc[b][2 * gg][r], Bui = acc[b][2 * gg + 1][r];
                sr += Lr * Bur - Li * Bui;
                si += Lr * Bui + Li * Bur;
                size_t ro = ((size_t)b * 2048 + l) * 1024;
                X[ro + cbase + lm]      = f2bf(sr);
                X[ro + cbase + lm + 16] = f2bf(si);
            }
        }
    }
}

// ---------------------------------------------------------------- GEMM2: y = X x Dt
__global__ __launch_bounds__(256, 2)
void gemm2(const unsigned short* __restrict__ X, const unsigned short* __restrict__ Dt,
           float* __restrict__ Y) {
    __shared__ __attribute__((aligned(16))) char LDS[65536];
    KSETUP(X, Dt)
    KMAIN()

#pragma unroll
    for (int mi = 0; mi < 8; ++mi) {
#pragma unroll
        for (int ni = 0; ni < 4; ++ni) {
            int c  = col0 + wc * 64 + ni * 16 + lm;
            int r0 = row0 + mi * 16 + lq * 4;
#pragma unroll
            for (int r = 0; r < 4; ++r)
                Y[(size_t)(r0 + r) * 1024 + c] = acc[mi][ni][r];
        }
    }
}

// ----------------------------------------------------------------
extern "C" void kernel_launch(void* const* d_in, const int* in_sizes, int n_in,
                              void* d_out, int out_size, void* d_ws, size_t ws_size,
                              hipStream_t stream) {
    const float* u      = (const float*)d_in[0];   // (8,2048,1024) f32
    const int*   len    = (const int*)d_in[1];     // (8,)
    const float* nu_log = (const float*)d_in[2];   // (512,)
    const float* th_log = (const float*)d_in[3];   // (512,)
    const float* Br     = (const float*)d_in[4];   // (1024,512)
    const float* Bi     = (const float*)d_in[5];   // (1024,512)
    const float* Cr     = (const float*)d_in[6];   // (512,1024)
    const float* Ci     = (const float*)d_in[7];   // (512,1024)
    float* y = (float*)d_out;                      // (8,2048,1024) f32

    char* ws = (char*)d_ws;
    unsigned short* A  = (unsigned short*)(ws);                 // 32 MB  (u bf16, rows permuted)
    unsigned short* X  = (unsigned short*)(ws + 33554432);      // 32 MB  (phase+cumsum result)
    unsigned short* Bt = (unsigned short*)(ws + 67108864);      //  2 MB
    unsigned short* Dt = (unsigned short*)(ws + 69206016);      //  2 MB

    prep<<<18432, 256, 0, stream>>>(u, Br, Bi, Cr, Ci, A, Bt, Dt);
    gemm1_fused<<<512, 256, 0, stream>>>(A, Bt, len, nu_log, th_log, X);
    gemm2<<<512, 256, 0, stream>>>(X, Dt, y);
}

// Round 6
// 224.370 us; speedup vs baseline: 1.0641x; 1.0141x over previous
//
#include <hip/hip_runtime.h>

typedef short bf16x8 __attribute__((ext_vector_type(8)));
typedef float f32x4 __attribute__((ext_vector_type(4)));

__device__ __forceinline__ unsigned short f2bf(float f) {
    unsigned u = __float_as_uint(f);
    u += 0x7FFFu + ((u >> 16) & 1u);      // round-to-nearest-even
    return (unsigned short)(u >> 16);
}
__device__ __forceinline__ float bf2f(unsigned short h) {
    return __uint_as_float(((unsigned)h) << 16);
}
__device__ __forceinline__ void gload_lds16(const void* g, void* l) {
    __builtin_amdgcn_global_load_lds(
        (const __attribute__((address_space(1))) void*)g,
        (__attribute__((address_space(3))) void*)l,
        16, 0, 0);
}

// ---------------------------------------------------------------- prep (small now):
// u-conversion is fused into gemm1's staging. Only Bt / Dt remain.
// blocks [0,1024): Bt[j][k] interleaved: g=j>>5, w=j&31, n=g*16+(w&15)
//   Bt[j][k] = (w<16 ? Br[k][n] : Bi[k][n])          (1024x1024 bf16)
// blocks [1024,2048): Dt[h][j]: Dt[h][j] = (w<16 ? Cr[n][h] : -Ci[n][h])
__global__ void prep(const float* __restrict__ Br, const float* __restrict__ Bi,
                     const float* __restrict__ Cr, const float* __restrict__ Ci,
                     unsigned short* __restrict__ Bt, unsigned short* __restrict__ Dt) {
    __shared__ unsigned short tile[32][33];
    int id = blockIdx.x;           // [0, 2048)
    int z  = id >> 10;             // 0: Bt, 1: Dt
    int t  = id & 1023;
    int jt = t >> 5, kt = t & 31;  // j-tile (32 cols of out), k/h-tile
    int tx = threadIdx.x & 31, ty = threadIdx.x >> 5;   // 32 x 8
    if (z == 0) {
        for (int i2 = ty; i2 < 32; i2 += 8) {          // i2 = k offset
            int k = kt * 32 + i2;
            float v = (tx < 16) ? Br[(size_t)k * 512 + jt * 16 + tx]
                                : Bi[(size_t)k * 512 + jt * 16 + (tx & 15)];
            tile[tx][i2] = f2bf(v);                    // tile[w][k]
        }
        __syncthreads();
        for (int i2 = ty; i2 < 32; i2 += 8)            // i2 = w
            Bt[(size_t)(jt * 32 + i2) * 1024 + kt * 32 + tx] = tile[i2][tx];
    } else {
        for (int i2 = ty; i2 < 32; i2 += 8) {          // i2 = w
            float v = (i2 < 16) ? Cr[(size_t)(jt * 16 + i2) * 1024 + kt * 32 + tx]
                                : -Ci[(size_t)(jt * 16 + (i2 & 15)) * 1024 + kt * 32 + tx];
            tile[i2][tx] = f2bf(v);                    // tile[w][h]
        }
        __syncthreads();
        for (int i2 = ty; i2 < 32; i2 += 8)            // i2 = h offset
            Dt[(size_t)(kt * 32 + i2) * 1024 + jt * 32 + tx] = tile[tx][i2];
    }
}

// ---------------------------------------------------------------- GEMM1 + fused phase/cumsum
// Round-0 proven structure (2-barrier loop, 128x256 tile, BK=32, 4 waves 2x2,
// wave tile 64x128, grid 512 = 2 blocks/CU). Changes vs round-0:
//  (1) A staged from u (f32) directly: per-thread float4 loads + f2bf + swizzled
//      ds_write (prep's A pass deleted; numerics bit-identical).
//  (2) LDS bank-conflict fix: slot ^= (row&3) within 64B rows, applied BOTH sides
//      (pre-XOR'd gload_lds source for B / swizzled ds_write for A; XOR'd read slot).
//      16-way -> 4-way (free-ish per m136).
__global__ __launch_bounds__(256, 2)
void gemm1_fused(const float* __restrict__ u, const unsigned short* __restrict__ Bt,
                 const int* __restrict__ len, const float* __restrict__ nu_log,
                 const float* __restrict__ th_log, unsigned short* __restrict__ X) {
    __shared__ unsigned short As[128 * 32];   // 8 KB
    __shared__ unsigned short Bs[256 * 32];   // 16 KB (reused as fp32 totals in epilogue)

    const int tid = threadIdx.x, wave = tid >> 6, lane = tid & 63;
    const int lm = lane & 15, lq = lane >> 4;
    const int wr = wave >> 1, wc = wave & 1;

    const int id = blockIdx.x, xcd = id & 7, j = id >> 3;
    const int p    = xcd * 16 + (j >> 2);   // l-panel: l in [p*16, p*16+16)
    const int col0 = (j & 3) * 256;

    f32x4 acc[4][8] = {};

    // A staging: thread covers tile-row r_ (0..127), k-half h2; row r_ = b*16+ll -> u row
    const int r_ = tid >> 1, h2 = tid & 1;
    const float4* su4 = (const float4*)(u + (size_t)((r_ >> 4) * 2048 + p * 16 + (r_ & 15)) * 1024)
                        + h2 * 4;
    char* wA0 = (char*)As + r_ * 64 + ((( 2 * h2     ) ^ (r_ & 3)) << 4);
    char* wA1 = (char*)As + r_ * 64 + ((( 2 * h2 + 1 ) ^ (r_ & 3)) << 4);

    // B staging via gload_lds, pre-XOR'd source slot (dest linear)
    const int xoff = ((tid & 3) ^ ((tid >> 2) & 3)) << 4;
    const char* gB0 = (const char*)Bt + (size_t)(col0 + (tid >> 2)) * 2048 + xoff;
    const char* gB1 = gB0 + 64 * 2048;
    const char* gB2 = gB1 + 64 * 2048;
    const char* gB3 = gB2 + 64 * 2048;
    char* lB0 = (char*)Bs + tid * 16;
    char* lB1 = lB0 + 4096; char* lB2 = lB1 + 4096; char* lB3 = lB2 + 4096;

    const int xr = (lq ^ (lm & 3)) << 4;   // swizzled read-slot byte offset

    for (int kk = 0; kk < 32; ++kk) {
        __syncthreads();
        gload_lds16(gB0, lB0); gload_lds16(gB1, lB1);
        gload_lds16(gB2, lB2); gload_lds16(gB3, lB3);
        gB0 += 64; gB1 += 64; gB2 += 64; gB3 += 64;
        float4 v0 = su4[0], v1 = su4[1], v2 = su4[2], v3 = su4[3];
        su4 += 8;
        union { unsigned short s[8]; bf16x8 v; } a0, a1;
        a0.s[0] = f2bf(v0.x); a0.s[1] = f2bf(v0.y); a0.s[2] = f2bf(v0.z); a0.s[3] = f2bf(v0.w);
        a0.s[4] = f2bf(v1.x); a0.s[5] = f2bf(v1.y); a0.s[6] = f2bf(v1.z); a0.s[7] = f2bf(v1.w);
        a1.s[0] = f2bf(v2.x); a1.s[1] = f2bf(v2.y); a1.s[2] = f2bf(v2.z); a1.s[3] = f2bf(v2.w);
        a1.s[4] = f2bf(v3.x); a1.s[5] = f2bf(v3.y); a1.s[6] = f2bf(v3.z); a1.s[7] = f2bf(v3.w);
        *(bf16x8*)wA0 = a0.v;
        *(bf16x8*)wA1 = a1.v;
        __syncthreads();

        bf16x8 af[4], bfr[8];
#pragma unroll
        for (int mi = 0; mi < 4; ++mi) {
            int m = wr * 64 + mi * 16 + lm;
            af[mi] = *(const bf16x8*)((const char*)As + m * 64 + xr);
        }
#pragma unroll
        for (int ni = 0; ni < 8; ++ni) {
            int n = wc * 128 + ni * 16 + lm;
            bfr[ni] = *(const bf16x8*)((const char*)Bs + n * 64 + xr);
        }
#pragma unroll
        for (int mi = 0; mi < 4; ++mi)
#pragma unroll
            for (int ni = 0; ni < 8; ++ni)
                acc[mi][ni] = __builtin_amdgcn_mfma_f32_16x16x32_bf16(
                    af[mi], bfr[ni], acc[mi][ni], 0, 0, 0);
    }

    // ---- fused epilogue (round-0 verbatim): Lambda^e phase multiply + cumsum over b ----
    __syncthreads();                        // K-loop LDS reads complete; Bs reusable
    float* tot = (float*)Bs;                // [wc][32][64 lanes] fp32, 16 KB
    const float inv2pi = 0.15915494309189535f;
    const float twopi  = 6.283185307179586f;

    int lenv[8];
#pragma unroll
    for (int b = 0; b < 8; ++b) lenv[b] = len[b];
    float nuv[4], rvv[4];
#pragma unroll
    for (int g = 0; g < 4; ++g) {
        int n = (col0 >> 1) + wc * 64 + g * 16 + lm;
        nuv[g] = __expf(nu_log[n]);
        rvv[g] = __expf(th_log[n]) * inv2pi;
    }
    const int l_lo = p * 16 + lq * 4;

    if (wr == 0) {
#pragma unroll
        for (int g = 0; g < 4; ++g) {
#pragma unroll
            for (int r = 0; r < 4; ++r) {
                float sr = 0.f, si = 0.f;
                int l = l_lo + r;
                float lp1 = (float)(l + 1);
#pragma unroll
                for (int mi = 0; mi < 4; ++mi) {
                    int b = mi;                           // wr==0: b = 0..3
                    float e = fmaxf((float)lenv[b] - lp1, 0.f);
                    float mag = __expf(-e * nuv[g]);
                    float ar = e * rvv[g]; ar -= floorf(ar);
                    float sn, cs; __sincosf(ar * twopi, &sn, &cs);
                    float Lr = mag * cs, Li = mag * sn;
                    float Bur = acc[mi][2 * g][r], Bui = acc[mi][2 * g + 1][r];
                    sr += Lr * Bur - Li * Bui;
                    si += Lr * Bui + Li * Bur;
                    size_t rowoff = ((size_t)b * 2048 + l) * 1024;
                    int c = col0 + wc * 128 + g * 32 + lm;
                    X[rowoff + c]      = f2bf(sr);
                    X[rowoff + c + 16] = f2bf(si);
                }
                int f = (g * 4 + r) * 2;
                tot[(wc * 32 + f) * 64 + lane]     = sr;
                tot[(wc * 32 + f + 1) * 64 + lane] = si;
            }
        }
    }
    __syncthreads();
    if (wr == 1) {
#pragma unroll
        for (int g = 0; g < 4; ++g) {
#pragma unroll
            for (int r = 0; r < 4; ++r) {
                int f = (g * 4 + r) * 2;
                float sr = tot[(wc * 32 + f) * 64 + lane];
                float si = tot[(wc * 32 + f + 1) * 64 + lane];
                int l = l_lo + r;
                float lp1 = (float)(l + 1);
#pragma unroll
                for (int mi = 0; mi < 4; ++mi) {
                    int b = 4 + mi;                       // wr==1: b = 4..7
                    float e = fmaxf((float)lenv[b] - lp1, 0.f);
                    float mag = __expf(-e * nuv[g]);
                    float ar = e * rvv[g]; ar -= floorf(ar);
                    float sn, cs; __sincosf(ar * twopi, &sn, &cs);
                    float Lr = mag * cs, Li = mag * sn;
                    float Bur = acc[mi][2 * g][r], Bui = acc[mi][2 * g + 1][r];
                    sr += Lr * Bur - Li * Bui;
                    si += Lr * Bui + Li * Bur;
                    size_t rowoff = ((size_t)b * 2048 + l) * 1024;
                    int c = col0 + wc * 128 + g * 32 + lm;
                    X[rowoff + c]      = f2bf(sr);
                    X[rowoff + c + 16] = f2bf(si);
                }
            }
        }
    }
}

// ---------------------------------------------------------------- GEMM2: y = X x Dt
// Round-0 structure + both-sides swizzle (pre-XOR'd gload_lds sources, XOR'd reads).
__global__ __launch_bounds__(256, 2)
void gemm2(const unsigned short* __restrict__ X, const unsigned short* __restrict__ Dt,
           float* __restrict__ Y) {
    __shared__ unsigned short As[128 * 32];
    __shared__ unsigned short Bs[256 * 32];

    const int tid = threadIdx.x, wave = tid >> 6, lane = tid & 63;
    const int lm = lane & 15, lq = lane >> 4;
    const int wr = wave >> 1, wc = wave & 1;

    const int id = blockIdx.x, xcd = id & 7, j = id >> 3;
    const int row0 = (xcd * 16 + (j >> 2)) * 128;
    const int col0 = (j & 3) * 256;

    f32x4 acc[4][8] = {};

    const int xoff = ((tid & 3) ^ ((tid >> 2) & 3)) << 4;
    const char* gA0 = (const char*)X  + (size_t)(row0 + (tid >> 2)) * 2048 + xoff;
    const char* gA1 = gA0 + 64 * 2048;
    const char* gB0 = (const char*)Dt + (size_t)(col0 + (tid >> 2)) * 2048 + xoff;
    const char* gB1 = gB0 + 64 * 2048;
    const char* gB2 = gB1 + 64 * 2048;
    const char* gB3 = gB2 + 64 * 2048;
    char* lA0 = (char*)As + tid * 16; char* lA1 = lA0 + 4096;
    char* lB0 = (char*)Bs + tid * 16;
    char* lB1 = lB0 + 4096; char* lB2 = lB1 + 4096; char* lB3 = lB2 + 4096;

    const int xr = (lq ^ (lm & 3)) << 4;

    for (int kk = 0; kk < 32; ++kk) {
        __syncthreads();
        gload_lds16(gA0, lA0); gload_lds16(gA1, lA1);
        gload_lds16(gB0, lB0); gload_lds16(gB1, lB1);
        gload_lds16(gB2, lB2); gload_lds16(gB3, lB3);
        gA0 += 64; gA1 += 64; gB0 += 64; gB1 += 64; gB2 += 64; gB3 += 64;
        __syncthreads();

        bf16x8 af[4], bfr[8];
#pragma unroll
        for (int mi = 0; mi < 4; ++mi) {
            int m = wr * 64 + mi * 16 + lm;
            af[mi] = *(const bf16x8*)((const char*)As + m * 64 + xr);
        }
#pragma unroll
        for (int ni = 0; ni < 8; ++ni) {
            int n = wc * 128 + ni * 16 + lm;
            bfr[ni] = *(const bf16x8*)((const char*)Bs + n * 64 + xr);
        }
#pragma unroll
        for (int mi = 0; mi < 4; ++mi)
#pragma unroll
            for (int ni = 0; ni < 8; ++ni)
                acc[mi][ni] = __builtin_amdgcn_mfma_f32_16x16x32_bf16(
                    af[mi], bfr[ni], acc[mi][ni], 0, 0, 0);
    }

#pragma unroll
    for (int mi = 0; mi < 4; ++mi) {
#pragma unroll
        for (int ni = 0; ni < 8; ++ni) {
            int c  = col0 + wc * 128 + ni * 16 + lm;
            int r0 = row0 + wr * 64 + mi * 16 + lq * 4;
#pragma unroll
            for (int r = 0; r < 4; ++r)
                Y[(size_t)(r0 + r) * 1024 + c] = acc[mi][ni][r];
        }
    }
}

// ----------------------------------------------------------------
extern "C" void kernel_launch(void* const* d_in, const int* in_sizes, int n_in,
                              void* d_out, int out_size, void* d_ws, size_t ws_size,
                              hipStream_t stream) {
    const float* u      = (const float*)d_in[0];   // (8,2048,1024) f32
    const int*   len    = (const int*)d_in[1];     // (8,)
    const float* nu_log = (const float*)d_in[2];   // (512,)
    const float* th_log = (const float*)d_in[3];   // (512,)
    const float* Br     = (const float*)d_in[4];   // (1024,512)
    const float* Bi     = (const float*)d_in[5];   // (1024,512)
    const float* Cr     = (const float*)d_in[6];   // (512,1024)
    const float* Ci     = (const float*)d_in[7];   // (512,1024)
    float* y = (float*)d_out;                      // (8,2048,1024) f32

    char* ws = (char*)d_ws;
    unsigned short* X  = (unsigned short*)(ws);                 // 32 MB  (phase+cumsum result)
    unsigned short* Bt = (unsigned short*)(ws + 33554432);      //  2 MB
    unsigned short* Dt = (unsigned short*)(ws + 35651584);      //  2 MB

    prep<<<2048, 256, 0, stream>>>(Br, Bi, Cr, Ci, Bt, Dt);
    gemm1_fused<<<512, 256, 0, stream>>>(u, Bt, len, nu_log, th_log, X);
    gemm2<<<512, 256, 0, stream>>>(X, Dt, y);
}

// Round 11
// 213.576 us; speedup vs baseline: 1.1178x; 1.0505x over previous
//
#include <hip/hip_runtime.h>

typedef short bf16x8 __attribute__((ext_vector_type(8)));
typedef float f32x4 __attribute__((ext_vector_type(4)));

__device__ __forceinline__ unsigned short f2bf(float f) {
    unsigned u = __float_as_uint(f);
    u += 0x7FFFu + ((u >> 16) & 1u);      // round-to-nearest-even
    return (unsigned short)(u >> 16);
}
__device__ __forceinline__ void gload_lds16(const void* g, void* l) {
    __builtin_amdgcn_global_load_lds(
        (const __attribute__((address_space(1))) void*)g,
        (__attribute__((address_space(3))) void*)l,
        16, 0, 0);
}

// ---------------------------------------------------------------- prep (r0 proven version):
// blocks [0,16384): u -> bf16 A' with row permutation A'[p*128+b*16+ll] = u[b*2048+p*16+ll]
// blocks [16384,17408): Bt[j][k], j=(g,w): n=g*16+(w&15); Bt = (w<16 ? Br[k][n] : Bi[k][n])
// blocks [17408,18432): Dt[h][j]: (w<16 ? Cr[n][h] : -Ci[n][h])
__global__ void prep(const float* __restrict__ u,
                     const float* __restrict__ Br, const float* __restrict__ Bi,
                     const float* __restrict__ Cr, const float* __restrict__ Ci,
                     unsigned short* __restrict__ A, unsigned short* __restrict__ Bt,
                     unsigned short* __restrict__ Dt) {
    int bid = blockIdx.x;
    if (bid < 16384) {
        int i = bid * 256 + threadIdx.x;
        int ro = i >> 8, c4 = i & 255;
        int p = ro >> 7, b = (ro >> 4) & 7, ll = ro & 15;
        int ri = b * 2048 + p * 16 + ll;
        float4 v = ((const float4*)u)[(size_t)ri * 256 + c4];
        ushort4 o; o.x = f2bf(v.x); o.y = f2bf(v.y); o.z = f2bf(v.z); o.w = f2bf(v.w);
        ((ushort4*)A)[i] = o;
        return;
    }
    __shared__ unsigned short tile[32][33];
    int id = bid - 16384;
    int z  = id >> 10;
    int t  = id & 1023;
    int jt = t >> 5, kt = t & 31;
    int tx = threadIdx.x & 31, ty = threadIdx.x >> 5;
    if (z == 0) {
        for (int i2 = ty; i2 < 32; i2 += 8) {
            int k = kt * 32 + i2;
            float v = (tx < 16) ? Br[(size_t)k * 512 + jt * 16 + tx]
                                : Bi[(size_t)k * 512 + jt * 16 + (tx & 15)];
            tile[tx][i2] = f2bf(v);
        }
        __syncthreads();
        for (int i2 = ty; i2 < 32; i2 += 8)
            Bt[(size_t)(jt * 32 + i2) * 1024 + kt * 32 + tx] = tile[i2][tx];
    } else {
        for (int i2 = ty; i2 < 32; i2 += 8) {
            float v = (i2 < 16) ? Cr[(size_t)(jt * 16 + i2) * 1024 + kt * 32 + tx]
                                : -Ci[(size_t)(jt * 16 + (i2 & 15)) * 1024 + kt * 32 + tx];
            tile[i2][tx] = f2bf(v);
        }
        __syncthreads();
        for (int i2 = ty; i2 < 32; i2 += 8)
            Dt[(size_t)(kt * 32 + i2) * 1024 + jt * 32 + tx] = tile[tx][i2];
    }
}

// ---------------------------------------------------------------- shared K-loop pieces
// 256x256 tile, BK=32, 8 waves (2wr x 4wc), wave tile 128x64, acc[8][4].
// Grid 256 = 1 block/CU; K=1024 -> 32 K-tiles.
// LDS: ring of 4 buffers x 32KB (A 16KB + B 16KB) = 128KB. 2 tile-rows per 128B LDS
// row; slot sg of LDS row jg holds global row 2jg+(snom>>2), quarter snom&3, with
// snom = sg^(jg&7); gload_lds dest LINEAR, global SOURCE inverse-permuted (rule 21).
// Read slot sr = (((lm&1)<<2)|lq) ^ (lm>>1) inverts it; 8 lanes/LDS-row cover all
// 8 slots bijectively -> conflict-free.
// Pipeline: stage K-tile t+3 during tile t; counted vmcnt(8) per tile retires tile
// t+1's 4 loads (each wave stages a disjoint portion); barrier after it publishes.
// Tail: vmcnt 4 -> 0 -> 0.
// A/B THIS ROUND: gemm1 = MERGED (1 barrier/tile, one 32-MFMA cluster);
//                 gemm2 = SPLIT  (2 phases, 4 barriers/tile). Only variable = phase
// granularity; layout/ring/vmcnt identical.

#define SBAR __builtin_amdgcn_sched_barrier(0)

#define KSETUP(AP, BP)                                                              \
    const int tid = threadIdx.x, lane = tid & 63, wave = tid >> 6;                  \
    const int lm = lane & 15, lq = lane >> 4;                                       \
    const int wr = wave >> 2, wc = wave & 3;                                        \
    const int id = blockIdx.x;                                                      \
    const int T = (id & 7) * 32 + (id >> 3);                                        \
    const int bm = T >> 2, bn = T & 3;                                              \
    const int row0 = bm * 256, col0 = bn * 256;                                     \
    const int jg = tid >> 3, sg = tid & 7;                                          \
    const int snom = sg ^ (jg & 7);                                                 \
    const int srow = 2 * jg + (snom >> 2);                                          \
    const int scol = (snom & 3) * 16;                                               \
    const char* gA = (const char*)(AP) + (size_t)(row0 + srow) * 2048 + scol;       \
    const char* gB = (const char*)(BP) + (size_t)(col0 + srow) * 2048 + scol;       \
    const int d0 = tid * 16;                                                        \
    const int sr = (((lm & 1) << 2) | lq) ^ (lm >> 1);                              \
    const char* rA = (char*)LDS + wr * 8192 + (lm >> 1) * 128 + sr * 16;            \
    const char* rB = (char*)LDS + 16384 + wc * 4096 + (lm >> 1) * 128 + sr * 16;    \
    f32x4 acc[8][4] = {};

#define STAGE_A(t_) do { size_t o_ = (size_t)(t_) * 64;                             \
    char* b_ = (char*)LDS + ((t_) & 3) * 32768;                                     \
    gload_lds16(gA + o_, b_ + d0);                                                  \
    gload_lds16(gA + o_ + 128 * 2048, b_ + d0 + 8192); } while (0)

#define STAGE_B(t_) do { size_t o_ = (size_t)(t_) * 64;                             \
    char* b_ = (char*)LDS + ((t_) & 3) * 32768 + 16384;                             \
    gload_lds16(gB + o_, b_ + d0);                                                  \
    gload_lds16(gB + o_ + 128 * 2048, b_ + d0 + 8192); } while (0)

// ---- MERGED tile: 1 barrier per K-tile -------------------------------------------
#define KTILE_M(t_, DOST, VMS) {                                                    \
    const char* pa = rA + ((t_) & 3) * 32768;                                       \
    const char* pb = rB + ((t_) & 3) * 32768;                                       \
    bf16x8 av[8], bv[4];                                                            \
    _Pragma("unroll")                                                               \
    for (int i_ = 0; i_ < 4; ++i_) av[i_] = *(const bf16x8*)(pa + i_ * 1024);       \
    _Pragma("unroll")                                                               \
    for (int i_ = 0; i_ < 4; ++i_) av[4 + i_] = *(const bf16x8*)(pa + 4096 + i_ * 1024); \
    _Pragma("unroll")                                                               \
    for (int i_ = 0; i_ < 4; ++i_) bv[i_] = *(const bf16x8*)(pb + i_ * 1024);       \
    if (DOST) { STAGE_A((t_) + 3); STAGE_B((t_) + 3); }                             \
    SBAR;                                                                           \
    asm volatile("s_waitcnt lgkmcnt(0)"); SBAR;                                     \
    __builtin_amdgcn_s_setprio(1);                                                  \
    _Pragma("unroll")                                                               \
    for (int mi_ = 0; mi_ < 8; ++mi_)                                               \
        _Pragma("unroll")                                                           \
        for (int ni_ = 0; ni_ < 4; ++ni_)                                           \
            acc[mi_][ni_] = __builtin_amdgcn_mfma_f32_16x16x32_bf16(                \
                av[mi_], bv[ni_], acc[mi_][ni_], 0, 0, 0);                          \
    __builtin_amdgcn_s_setprio(0);                                                  \
    SBAR;                                                                           \
    asm volatile("s_waitcnt vmcnt(" VMS ")");                                       \
    __builtin_amdgcn_s_barrier(); SBAR;                                             \
}

#define KMAIN_M()                                                                   \
    STAGE_A(0); STAGE_B(0); STAGE_A(1); STAGE_B(1); STAGE_A(2); STAGE_B(2);         \
    SBAR;                                                                           \
    asm volatile("s_waitcnt vmcnt(8)");                                             \
    __builtin_amdgcn_s_barrier(); SBAR;                                             \
    for (int t = 0; t < 29; ++t) { KTILE_M(t, 1, "8") }                             \
    KTILE_M(29, 0, "4")                                                             \
    KTILE_M(30, 0, "0")                                                             \
    KTILE_M(31, 0, "0")

// ---- SPLIT tile: 2 phases, 4 barriers per K-tile ---------------------------------
#define KTILE_S(t_, DOST, VMS) {                                                    \
    const char* pa = rA + ((t_) & 3) * 32768;                                       \
    const char* pb = rB + ((t_) & 3) * 32768;                                       \
    bf16x8 av[4], bv[4];                                                            \
    _Pragma("unroll")                                                               \
    for (int i_ = 0; i_ < 4; ++i_) av[i_] = *(const bf16x8*)(pa + i_ * 1024);       \
    _Pragma("unroll")                                                               \
    for (int i_ = 0; i_ < 4; ++i_) bv[i_] = *(const bf16x8*)(pb + i_ * 1024);       \
    if (DOST) { STAGE_A((t_) + 3); }                                                \
    SBAR; __builtin_amdgcn_s_barrier();                                             \
    asm volatile("s_waitcnt lgkmcnt(0)"); SBAR;                                     \
    __builtin_amdgcn_s_setprio(1);                                                  \
    _Pragma("unroll")                                                               \
    for (int mi_ = 0; mi_ < 4; ++mi_)                                               \
        _Pragma("unroll")                                                           \
        for (int ni_ = 0; ni_ < 4; ++ni_)                                           \
            acc[mi_][ni_] = __builtin_amdgcn_mfma_f32_16x16x32_bf16(                \
                av[mi_], bv[ni_], acc[mi_][ni_], 0, 0, 0);                          \
    __builtin_amdgcn_s_setprio(0);                                                  \
    SBAR; __builtin_amdgcn_s_barrier(); SBAR;                                       \
    _Pragma("unroll")                                                               \
    for (int i_ = 0; i_ < 4; ++i_) av[i_] = *(const bf16x8*)(pa + 4096 + i_ * 1024);\
    if (DOST) { STAGE_B((t_) + 3); }                                                \
    SBAR; __builtin_amdgcn_s_barrier();                                             \
    asm volatile("s_waitcnt lgkmcnt(0)"); SBAR;                                     \
    __builtin_amdgcn_s_setprio(1);                                                  \
    _Pragma("unroll")                                                               \
    for (int mi_ = 0; mi_ < 4; ++mi_)                                               \
        _Pragma("unroll")                                                           \
        for (int ni_ = 0; ni_ < 4; ++ni_)                                           \
            acc[4 + mi_][ni_] = __builtin_amdgcn_mfma_f32_16x16x32_bf16(            \
                av[mi_], bv[ni_], acc[4 + mi_][ni_], 0, 0, 0);                      \
    __builtin_amdgcn_s_setprio(0);                                                  \
    SBAR;                                                                           \
    asm volatile("s_waitcnt vmcnt(" VMS ")");                                       \
    __builtin_amdgcn_s_barrier(); SBAR;                                             \
}

#define KMAIN_S()                                                                   \
    STAGE_A(0); STAGE_B(0); STAGE_A(1); STAGE_B(1); STAGE_A(2); STAGE_B(2);         \
    SBAR;                                                                           \
    asm volatile("s_waitcnt vmcnt(8)");                                             \
    __builtin_amdgcn_s_barrier(); SBAR;                                             \
    for (int t = 0; t < 29; ++t) { KTILE_S(t, 1, "8") }                             \
    KTILE_S(29, 0, "4")                                                             \
    KTILE_S(30, 0, "0")                                                             \
    KTILE_S(31, 0, "0")

// ---------------------------------------------------------------- GEMM1 (MERGED) + fused epilogue
// Wave wr owns l-panel pnl = 2*bm + wr (16 l's x all 8 batches, b == acc m-block):
// phase multiply + cumsum over b fully in-register.
__global__ __launch_bounds__(512, 2)
void gemm1_fused(const unsigned short* __restrict__ A, const unsigned short* __restrict__ Bt,
                 const int* __restrict__ len, const float* __restrict__ nu_log,
                 const float* __restrict__ th_log, unsigned short* __restrict__ X) {
    __shared__ __attribute__((aligned(16))) char LDS[131072];   // 4-ring x 32 KB
    KSETUP(A, Bt)
    KMAIN_M()

    const float inv2pi = 0.15915494309189535f;
    const float twopi  = 6.283185307179586f;
    int lenv[8];
#pragma unroll
    for (int b = 0; b < 8; ++b) lenv[b] = len[b];
    const int pnl  = 2 * bm + wr;
    const int l_lo = pnl * 16 + lq * 4;
#pragma unroll
    for (int gg = 0; gg < 2; ++gg) {
        const int cbase = col0 + wc * 64 + gg * 32;    // real at +lm, imag at +16+lm
        const int n = (cbase >> 5) * 16 + lm;
        const float nu = __expf(nu_log[n]);
        const float rv = __expf(th_log[n]) * inv2pi;
#pragma unroll
        for (int r = 0; r < 4; ++r) {
            const int l = l_lo + r;
            const float lp1 = (float)(l + 1);
            float sr_ = 0.f, si_ = 0.f;
#pragma unroll
            for (int b = 0; b < 8; ++b) {              // in-register cumsum over b
                float e = fmaxf((float)lenv[b] - lp1, 0.f);
                float mag = __expf(-e * nu);
                float ar = e * rv; ar -= floorf(ar);
                float sn, cs; __sincosf(ar * twopi, &sn, &cs);
                float Lr = mag * cs, Li = mag * sn;
                float Bur = acc[b][2 * gg][r], Bui = acc[b][2 * gg + 1][r];
                sr_ += Lr * Bur - Li * Bui;
                si_ += Lr * Bui + Li * Bur;
                size_t ro = ((size_t)b * 2048 + l) * 1024;
                X[ro + cbase + lm]      = f2bf(sr_);
                X[ro + cbase + lm + 16] = f2bf(si_);
            }
        }
    }
}

// ---------------------------------------------------------------- GEMM2 (SPLIT): y = X x Dt
__global__ __launch_bounds__(512, 2)
void gemm2(const unsigned short* __restrict__ X, const unsigned short* __restrict__ Dt,
           float* __restrict__ Y) {
    __shared__ __attribute__((aligned(16))) char LDS[131072];
    KSETUP(X, Dt)
    KMAIN_S()

#pragma unroll
    for (int mi = 0; mi < 8; ++mi) {
#pragma unroll
        for (int ni = 0; ni < 4; ++ni) {
            int c  = col0 + wc * 64 + ni * 16 + lm;
            int r0 = row0 + wr * 128 + mi * 16 + lq * 4;
#pragma unroll
            for (int r = 0; r < 4; ++r)
                Y[(size_t)(r0 + r) * 1024 + c] = acc[mi][ni][r];
        }
    }
}

// ----------------------------------------------------------------
extern "C" void kernel_launch(void* const* d_in, const int* in_sizes, int n_in,
                              void* d_out, int out_size, void* d_ws, size_t ws_size,
                              hipStream_t stream) {
    const float* u      = (const float*)d_in[0];   // (8,2048,1024) f32
    const int*   len    = (const int*)d_in[1];     // (8,)
    const float* nu_log = (const float*)d_in[2];   // (512,)
    const float* th_log = (const float*)d_in[3];   // (512,)
    const float* Br     = (const float*)d_in[4];   // (1024,512)
    const float* Bi     = (const float*)d_in[5];   // (1024,512)
    const float* Cr     = (const float*)d_in[6];   // (512,1024)
    const float* Ci     = (const float*)d_in[7];   // (512,1024)
    float* y = (float*)d_out;                      // (8,2048,1024) f32

    char* ws = (char*)d_ws;
    unsigned short* A  = (unsigned short*)(ws);                 // 32 MB  (u bf16, rows permuted)
    unsigned short* X  = (unsigned short*)(ws + 33554432);      // 32 MB  (phase+cumsum result)
    unsigned short* Bt = (unsigned short*)(ws + 67108864);      //  2 MB
    unsigned short* Dt = (unsigned short*)(ws + 69206016);      //  2 MB

    prep<<<18432, 256, 0, stream>>>(u, Br, Bi, Cr, Ci, A, Bt, Dt);
    gemm1_fused<<<256, 512, 0, stream>>>(A, Bt, len, nu_log, th_log, X);
    gemm2<<<256, 512, 0, stream>>>(X, Dt, y);
}